// Round 11
// baseline (868.591 us; speedup 1.0000x reference)
//
#include <hip/hip_runtime.h>
#include <cstddef>
#include <cstdint>

// ---------------- problem constants ----------------
#define HEADS   4
#define C2c     384
#define HPc     63
#define WPc     63
#define NWc     81
#define BATCH   8
#define TOKP    (BATCH*HPc*WPc)   // 31752 windowed rows
#define TOKC    (BATCH*60*60)     // 28800 cropped tokens
#define MLPH    1536
#define TPB     3969              // windowed rows per batch
#define CONVK   3456              // 384*9
#define CONVN   192

typedef __attribute__((ext_vector_type(8))) short short8;
typedef __attribute__((ext_vector_type(4))) float f32x4;
typedef unsigned short u16;

__device__ __forceinline__ u16 f2bf(float f) {
  unsigned u = __float_as_uint(f);
  u += 0x7fff + ((u >> 16) & 1);           // RNE
  return (u16)(u >> 16);
}
__device__ __forceinline__ float bf2f(u16 b) { return __uint_as_float((unsigned)b << 16); }

// global -> LDS async 16B: dest = wave-uniform base + lane*16; src per-lane
#define GLOAD16(gp, lp) __builtin_amdgcn_global_load_lds( \
    (const __attribute__((address_space(1))) unsigned*)(gp), \
    (__attribute__((address_space(3))) unsigned*)(lp), 16, 0, 0)

// bijective XCD swizzle (m204)
__device__ __forceinline__ int xcd_swizzle(int orig, int nwg) {
  int q = nwg >> 3, r = nwg & 7;
  int xcd = orig & 7, off = orig >> 3;
  return (xcd < r ? xcd*(q+1) : r*(q+1) + (xcd - r)*q) + off;
}

// ---------------- block reduce (384 threads, 6 waves) ----------------
__device__ __forceinline__ float2 block_reduce_384(float v, float* red) {
  __syncthreads();
  float s = v, q = v * v;
  #pragma unroll
  for (int o = 32; o > 0; o >>= 1) {
    s += __shfl_down(s, o);
    q += __shfl_down(q, o);
  }
  int w = threadIdx.x >> 6;
  if ((threadIdx.x & 63) == 0) { red[2*w] = s; red[2*w+1] = q; }
  __syncthreads();
  float ts = red[0]+red[2]+red[4]+red[6]+red[8]+red[10];
  float tq = red[1]+red[3]+red[5]+red[7]+red[9]+red[11];
  return make_float2(ts, tq);
}

// ---------------- K1a: LN1 stats + LN(n1)+roll+window -> wbuf bf16 ----------------
__global__ __launch_bounds__(384)
void k1a_kernel(const float* __restrict__ x, const float* __restrict__ g,
                const float* __restrict__ nw, const float* __restrict__ nb,
                const float* __restrict__ n1w, const float* __restrict__ n1b,
                float* __restrict__ musig, u16* __restrict__ wbuf)
{
  __shared__ float red[12];
  int t = blockIdx.x;
  int b = t / (HPc*WPc);
  int rem = t - b*(HPc*WPc);
  int i = rem / WPc, j = rem - (rem / WPc)*WPc;
  int c = threadIdx.x;

  float v = 0.f;
  if (i < 60 && j < 60) {
    if (c < 192) v = x[(((size_t)b*192 + c)*60 + i)*60 + j];
    else         v = g[(((size_t)b*192 + (c-192))*60 + i)*60 + j];
  }
  float2 ss = block_reduce_384(v, red);
  float mu  = ss.x * (1.f/384.f);
  float var = ss.y * (1.f/384.f) - mu*mu;
  float rs  = rsqrtf(var + 1e-5f);
  if (c == 0) { musig[2*t] = mu; musig[2*t+1] = rs; }
  float zi  = (v - mu) * rs * nw[c] + nb[c];
  float2 s2 = block_reduce_384(zi, red);
  float mu2  = s2.x * (1.f/384.f);
  float var2 = s2.y * (1.f/384.f) - mu2*mu2;
  float zn = (zi - mu2) * rsqrtf(var2 + 1e-5f) * n1w[c] + n1b[c];
  int ai = i - 3; if (ai < 0) ai += HPc;
  int aj = j - 3; if (aj < 0) aj += WPc;
  int win = (ai/7)*9 + (aj/7);
  int tok = (ai%7)*7 + (aj%7);
  wbuf[(((size_t)b*NWc + win)*49 + tok)*C2c + c] = f2bf(zn);
}

// ---------------- K1b: recompute z fp32 (cropped) from x,g and stored mu/rsig ----------------
__global__ __launch_bounds__(384)
void k1b_kernel(const float* __restrict__ x, const float* __restrict__ g,
                const float* __restrict__ nw, const float* __restrict__ nb,
                const float* __restrict__ musig, float* __restrict__ z)
{
  int tc = blockIdx.x;
  int b = tc / 3600;
  int rem = tc - b*3600;
  int i = rem / 60, j = rem - (rem/60)*60;
  int t = b*(HPc*WPc) + i*WPc + j;
  int c = threadIdx.x;
  float v;
  if (c < 192) v = x[(((size_t)b*192 + c)*60 + i)*60 + j];
  else         v = g[(((size_t)b*192 + (c-192))*60 + i)*60 + j];
  float mu = musig[2*t], rs = musig[2*t+1];
  z[(size_t)tc*C2c + c] = (v - mu) * rs * nw[c] + nb[c];
}

// ---------------- LN (n2): z fp32 -> out bf16 ----------------
__global__ __launch_bounds__(384)
void ln2_kernel(const float* __restrict__ z, const float* __restrict__ nw,
                const float* __restrict__ nb, u16* __restrict__ out)
{
  __shared__ float red[12];
  int tc = blockIdx.x;
  int c = threadIdx.x;
  float v = z[(size_t)tc*C2c + c];
  float2 ss = block_reduce_384(v, red);
  float mu  = ss.x * (1.f/384.f);
  float var = ss.y * (1.f/384.f) - mu*mu;
  out[(size_t)tc*C2c + c] = f2bf((v - mu) * rsqrtf(var + 1e-5f) * nw[c] + nb[c]);
}

// ---------------- one-shot weight prep: casts + conv transpose/split + zero pad ----------------
__global__ __launch_bounds__(256)
void prep_kernel(const float* __restrict__ qkv_w, const float* __restrict__ proj_w,
                 const float* __restrict__ fc1_w, const float* __restrict__ fc2_w,
                 const float* __restrict__ conv_w,
                 u16* __restrict__ qkvw, u16* __restrict__ pw,
                 u16* __restrict__ f1w, u16* __restrict__ f2w,
                 u16* __restrict__ cvwh, u16* __restrict__ cvwl, u16* __restrict__ zpad)
{
  int t = blockIdx.x*256 + threadIdx.x;
  if (t < 442368) { qkvw[t] = f2bf(qkv_w[t]); return; }
  t -= 442368;
  if (t < 147456) { pw[t] = f2bf(proj_w[t]); return; }
  t -= 147456;
  if (t < 589824) { f1w[t] = f2bf(fc1_w[t]); return; }
  t -= 589824;
  if (t < 589824) { f2w[t] = f2bf(fc2_w[t]); return; }
  t -= 589824;
  if (t < CONVN*CONVK) {
    int oc = t / CONVK, k = t - oc*CONVK;
    int p = k / 384, c = k - p*384;
    float v = conv_w[((size_t)oc*384 + c)*9 + p];
    u16 h = f2bf(v);
    cvwh[t] = h;
    cvwl[t] = f2bf(v - bf2f(h));
    return;
  }
  t -= CONVN*CONVK;
  if (t < 128) zpad[t] = 0;
}

// ---------------- MFMA GEMM (128x128, BK=64, single bf16 weight, XCD swizzle) ----------------
// EPI 0: bf16 store  EPI 1: z scatter-add (proj)  EPI 2: GELU bf16 (fc1)
// EPI 3: z += val(+bias)  EPI 4: Cb = bf16(val(+bias) + z)  (final fc2; z not written)
template<int EPI>
__global__ __launch_bounds__(256)
void mfma_gemm(const u16* __restrict__ A, const u16* __restrict__ B,
               const float* __restrict__ bias, u16* __restrict__ Cb, float* __restrict__ zbuf,
               int M, int N, int K, int ldb, int addbias)
{
  __shared__ u16 As [128*64];
  __shared__ u16 Bs [128*64];
  int tid = threadIdx.x;
  int lane = tid & 63, w = tid >> 6;
  int wr = w >> 1, wc = w & 1;
  int nwg = gridDim.x * gridDim.y;
  int swz = xcd_swizzle(blockIdx.y*gridDim.x + blockIdx.x, nwg);
  int bx = swz % gridDim.x, by = swz / gridDim.x;
  int m0 = by * 128, n0 = bx * 128;
  int srow = lane >> 3, sslot = (lane & 7) ^ srow;

  f32x4 acc[4][4];
  #pragma unroll
  for (int i = 0; i < 4; ++i)
    #pragma unroll
    for (int j = 0; j < 4; ++j) acc[i][j] = (f32x4){0.f,0.f,0.f,0.f};

  char* AsB = (char*)As; char* BsB = (char*)Bs;
  int r15 = lane & 15, kq = lane >> 4;

  for (int k0 = 0; k0 < K; k0 += 64) {
    #pragma unroll
    for (int i = 0; i < 4; ++i) {
      int rblk = w*4 + i;
      int ar = m0 + rblk*8 + srow; if (ar >= M) ar = M - 1;
      int br = n0 + rblk*8 + srow;
      GLOAD16(A + (size_t)ar*K   + k0 + sslot*8, AsB + rblk*1024);
      GLOAD16(B + (size_t)br*ldb + k0 + sslot*8, BsB + rblk*1024);
    }
    __syncthreads();
    #pragma unroll
    for (int ks = 0; ks < 2; ++ks) {
      int slog = ks*4 + kq;
      short8 af[4], bf[4];
      #pragma unroll
      for (int mi = 0; mi < 4; ++mi) {
        int row = wr*64 + mi*16 + r15;
        af[mi] = *(const short8*)(AsB + row*128 + ((slog ^ (row&7))<<4));
      }
      #pragma unroll
      for (int ni = 0; ni < 4; ++ni) {
        int row = wc*64 + ni*16 + r15;
        bf[ni] = *(const short8*)(BsB + row*128 + ((slog ^ (row&7))<<4));
      }
      #pragma unroll
      for (int mi = 0; mi < 4; ++mi)
        #pragma unroll
        for (int ni = 0; ni < 4; ++ni)
          acc[mi][ni] = __builtin_amdgcn_mfma_f32_16x16x32_bf16(af[mi], bf[ni], acc[mi][ni], 0, 0, 0);
    }
    __syncthreads();
  }

  int fq = lane >> 4, fr = lane & 15;
  #pragma unroll
  for (int mi = 0; mi < 4; ++mi) {
    #pragma unroll
    for (int j = 0; j < 4; ++j) {
      int m = m0 + wr*64 + mi*16 + fq*4 + j;
      if (m >= M) continue;
      int zrow = 0; bool zok = true;
      if (EPI == 1) {
        int b = m / TPB;
        int rem = m - b*TPB;
        int win = rem / 49, tok = rem - (rem/49)*49;
        int wh = win/9, ww = win - (win/9)*9;
        int th = tok/7, tw = tok - (tok/7)*7;
        int oi = wh*7 + th + 3; if (oi >= HPc) oi -= HPc;
        int oj = ww*7 + tw + 3; if (oj >= WPc) oj -= WPc;
        zok = (oi < 60 && oj < 60);
        zrow = (b*60 + oi)*60 + oj;
      }
      #pragma unroll
      for (int ni = 0; ni < 4; ++ni) {
        int n = n0 + wc*64 + ni*16 + fr;
        float val = acc[mi][ni][j];
        if (EPI == 0) {
          Cb[(size_t)m*N + n] = f2bf(val + bias[n]);
        } else if (EPI == 1) {
          if (zok) zbuf[(size_t)zrow*C2c + n] += val + bias[n];
        } else if (EPI == 2) {
          float vv = val + bias[n];
          float ge = 0.5f*vv*(1.f + erff(vv*0.70710678118654752f));
          Cb[(size_t)m*N + n] = f2bf(ge);
        } else if (EPI == 3) {
          float vv = val + (addbias ? bias[n] : 0.f);
          zbuf[(size_t)m*C2c + n] += vv;
        } else { // EPI == 4: final fc2 chunk — y = val + z, z NOT rewritten (dead after)
          float vv = val + (addbias ? bias[n] : 0.f) + zbuf[(size_t)m*C2c + n];
          Cb[(size_t)m*C2c + n] = f2bf(vv);
        }
      }
    }
  }
}

// ---------------- conv im2col MFMA: BM=64, BN=64, BK=128 as 2x64-col half-tiles ----------------
// Half-tiles keep the 128B LDS row stride (8 slots x 16B = all 32 banks once) -> conflict-free,
// while BK=128 halves the barrier count vs BK=64 (27 K-steps, 32 MFMA/wave/step).
__global__ __launch_bounds__(256)
void mfma_conv(const u16* __restrict__ Y, const u16* __restrict__ Bh, const u16* __restrict__ Bl,
               const float* __restrict__ cb, const float* __restrict__ xres,
               const u16* __restrict__ zpad, float* __restrict__ outp)
{
  __shared__ u16 As [2*64*64];   // 16 KB: [half][64 rows][8 slots x 16B]
  __shared__ u16 Bsh[2*64*64];   // 16 KB
  __shared__ u16 Bsl[2*64*64];   // 16 KB -> 48 KB total, 3 blocks/CU
  int tid = threadIdx.x;
  int lane = tid & 63, w = tid >> 6;
  int wr = w >> 1, wc = w & 1;
  int nwg = gridDim.x * gridDim.y;   // 3*450 = 1350
  int swz = xcd_swizzle(blockIdx.y*gridDim.x + blockIdx.x, nwg);
  int bx = swz % 3, by = swz / 3;
  int m0 = by * 64, n0 = bx * 64;
  int srow = lane >> 3, sslot = (lane & 7) ^ srow;   // row-in-chunk, pre-swizzled slot

  f32x4 acc[2][2];
  #pragma unroll
  for (int i = 0; i < 2; ++i)
    #pragma unroll
    for (int j = 0; j < 2; ++j) acc[i][j] = (f32x4){0.f,0.f,0.f,0.f};

  // chunk c (0..15): half = c>>3, rows (c&7)*8 + srow; wave w stages chunks {w, w+4, w+8, w+12}
  int pbA[4], ohA[4], owA[4], colA[4], cA[4];
  #pragma unroll
  for (int i = 0; i < 4; ++i) {
    cA[i] = w + i*4;
    int row = (cA[i] & 7)*8 + srow;
    int pix = m0 + row;
    int pb = pix / 3600;
    int prem = pix - pb*3600;
    pbA[i] = pb; ohA[i] = prem / 60; owA[i] = prem - (prem/60)*60;
    colA[i] = (cA[i] >> 3)*64 + sslot*8;            // half offset + pre-swizzled col
  }
  int brB[4], colB[4], cB[4];
  #pragma unroll
  for (int j = 0; j < 4; ++j) {
    cB[j] = w + j*4;
    brB[j] = n0 + (cB[j] & 7)*8 + srow;             // always < 192
    colB[j] = (cB[j] >> 3)*64 + sslot*8;
  }

  char* AsB = (char*)As; char* BhB = (char*)Bsh; char* BlB = (char*)Bsl;
  int r15 = lane & 15, kq = lane >> 4;

  for (int k0 = 0; k0 < CONVK; k0 += 128) {
    int p  = k0 / 384;                 // tap constant within BK=128 (384 % 128 == 0)
    int c0 = k0 - p*384;
    int dh = p/3 - 1, dw = (p - (p/3)*3) - 1;
    #pragma unroll
    for (int j = 0; j < 4; ++j) {
      GLOAD16(Bh + (size_t)brB[j]*CONVK + k0 + colB[j], BhB + cB[j]*1024);
      GLOAD16(Bl + (size_t)brB[j]*CONVK + k0 + colB[j], BlB + cB[j]*1024);
    }
    #pragma unroll
    for (int i = 0; i < 4; ++i) {
      int ih = ohA[i] + dh, iw = owA[i] + dw;
      const u16* src = ((unsigned)ih < 60u && (unsigned)iw < 60u)
        ? Y + ((size_t)pbA[i]*3600 + ih*60 + iw)*C2c + c0 + colA[i]
        : zpad;
      GLOAD16(src, AsB + cA[i]*1024);
    }
    __syncthreads();
    #pragma unroll
    for (int h = 0; h < 2; ++h) {
      #pragma unroll
      for (int ks = 0; ks < 2; ++ks) {
        int slog = ks*4 + kq;
        short8 af[2], bh2[2], bl2[2];
        #pragma unroll
        for (int mi = 0; mi < 2; ++mi) {
          int row = wr*32 + mi*16 + r15;
          af[mi] = *(const short8*)(AsB + h*8192 + row*128 + ((slog ^ (row&7))<<4));
        }
        #pragma unroll
        for (int ni = 0; ni < 2; ++ni) {
          int row = wc*32 + ni*16 + r15;
          int off = h*8192 + row*128 + ((slog ^ (row&7))<<4);
          bh2[ni] = *(const short8*)(BhB + off);
          bl2[ni] = *(const short8*)(BlB + off);
        }
        #pragma unroll
        for (int mi = 0; mi < 2; ++mi)
          #pragma unroll
          for (int ni = 0; ni < 2; ++ni) {
            acc[mi][ni] = __builtin_amdgcn_mfma_f32_16x16x32_bf16(af[mi], bh2[ni], acc[mi][ni], 0, 0, 0);
            acc[mi][ni] = __builtin_amdgcn_mfma_f32_16x16x32_bf16(af[mi], bl2[ni], acc[mi][ni], 0, 0, 0);
          }
      }
    }
    __syncthreads();
  }

  int fq = lane >> 4, fr = lane & 15;
  #pragma unroll
  for (int mi = 0; mi < 2; ++mi) {
    #pragma unroll
    for (int j = 0; j < 4; ++j) {
      int m = m0 + wr*32 + mi*16 + fq*4 + j;          // pixel id < 28800
      int pb = m / 3600;
      int rem = m - pb*3600;
      int oh = rem / 60, ow = rem - (rem/60)*60;
      #pragma unroll
      for (int ni = 0; ni < 2; ++ni) {
        int oc = n0 + wc*32 + ni*16 + fr;             // < 192
        size_t oi = ((size_t)pb*192 + oc)*3600 + oh*60 + ow;
        outp[oi] = acc[mi][ni][j] + cb[oc] + xres[oi];
      }
    }
  }
}

// ---------------- windowed attention (register-tiled) ----------------
#define QS_STRIDE 100
#define VS_STRIDE 104
#define SS_STRIDE 53

__global__ __launch_bounds__(256)
void attn_kernel(const u16* __restrict__ qkv, const float* __restrict__ rpb,
                 u16* __restrict__ out)
{
  __shared__ float qs[52*QS_STRIDE];
  __shared__ float ks[52*QS_STRIDE];
  __shared__ float S[52*SS_STRIDE];
  int blk = blockIdx.x;
  int h   = blk & 3;
  int bw  = blk >> 2;
  int win = bw % NWc;
  const u16* base = qkv + (size_t)bw*49*1152;
  int tid = threadIdx.x;

  for (int t2 = tid; t2 < 588; t2 += 256) {
    int r = t2 / 12, dq = t2 - (t2/12)*12;
    short8 qv = *(const short8*)(base + r*1152 +       h*96 + dq*8);
    short8 kv = *(const short8*)(base + r*1152 + 384 + h*96 + dq*8);
    #pragma unroll
    for (int e = 0; e < 8; ++e) {
      qs[r*QS_STRIDE + dq*8 + e] = bf2f((u16)qv[e]);
      ks[r*QS_STRIDE + dq*8 + e] = bf2f((u16)kv[e]);
    }
  }
  __syncthreads();

  const float scale = 0.1020620726159657f;
  int wh = win / 9, ww = win - (win/9)*9;

  if (tid < 169) {
    int tr = tid / 13, tc = tid - (tid/13)*13;
    int r0 = tr*4, c0 = tc*4;
    float a[4][4] = {};
    for (int k0 = 0; k0 < 96; k0 += 4) {
      float4 qv[4], kv4[4];
      #pragma unroll
      for (int i = 0; i < 4; ++i) qv[i]  = *(const float4*)&qs[(r0+i)*QS_STRIDE + k0];
      #pragma unroll
      for (int j = 0; j < 4; ++j) kv4[j] = *(const float4*)&ks[(c0+j)*QS_STRIDE + k0];
      #pragma unroll
      for (int i = 0; i < 4; ++i)
        #pragma unroll
        for (int j = 0; j < 4; ++j)
          a[i][j] += qv[i].x*kv4[j].x + qv[i].y*kv4[j].y + qv[i].z*kv4[j].z + qv[i].w*kv4[j].w;
    }
    #pragma unroll
    for (int i = 0; i < 4; ++i) {
      int r = r0 + i;
      if (r < 49) {
        int r1 = r/7, c1 = r - (r/7)*7;
        int hp1 = wh*7 + r1, wp1 = ww*7 + c1;
        int g1 = (hp1 < 56 ? 0 : (hp1 < 60 ? 1 : 2))*3 + (wp1 < 56 ? 0 : (wp1 < 60 ? 1 : 2));
        #pragma unroll
        for (int j = 0; j < 4; ++j) {
          int c = c0 + j;
          if (c < 49) {
            int r2 = c/7, c2 = c - (c/7)*7;
            float s = a[i][j]*scale + rpb[((r1 - r2 + 6)*13 + (c1 - c2 + 6))*HEADS + h];
            int hp2 = wh*7 + r2, wp2 = ww*7 + c2;
            int g2 = (hp2 < 56 ? 0 : (hp2 < 60 ? 1 : 2))*3 + (wp2 < 56 ? 0 : (wp2 < 60 ? 1 : 2));
            if (g1 != g2) s -= 100.f;
            S[r*SS_STRIDE + c] = s;
          }
        }
      }
    }
  }
  __syncthreads();

  for (int t2 = tid; t2 < 588; t2 += 256) {
    int r = t2 / 12, dq = t2 - (t2/12)*12;
    short8 vv = *(const short8*)(base + r*1152 + 768 + h*96 + dq*8);
    #pragma unroll
    for (int e = 0; e < 8; ++e) ks[r*VS_STRIDE + dq*8 + e] = bf2f((u16)vv[e]);
  }
  if (tid < 49) {
    float mx = -1e30f;
    for (int c = 0; c < 49; ++c) mx = fmaxf(mx, S[tid*SS_STRIDE + c]);
    float sum = 0.f;
    for (int c = 0; c < 49; ++c) { float e = expf(S[tid*SS_STRIDE + c] - mx); S[tid*SS_STRIDE + c] = e; sum += e; }
    float inv = 1.f / sum;
    for (int c = 0; c < 49; ++c) S[tid*SS_STRIDE + c] *= inv;
  }
  __syncthreads();

  if (tid < 156) {
    int tr2 = tid / 12, tc2 = tid - (tid/12)*12;
    int r0 = tr2*4, d0 = tc2*8;
    float o[4][8] = {};
    for (int c = 0; c < 49; ++c) {
      float4 v0 = *(const float4*)&ks[c*VS_STRIDE + d0];
      float4 v1 = *(const float4*)&ks[c*VS_STRIDE + d0 + 4];
      #pragma unroll
      for (int i = 0; i < 4; ++i) {
        float sv = S[(r0+i)*SS_STRIDE + c];
        o[i][0] += sv*v0.x; o[i][1] += sv*v0.y; o[i][2] += sv*v0.z; o[i][3] += sv*v0.w;
        o[i][4] += sv*v1.x; o[i][5] += sv*v1.y; o[i][6] += sv*v1.z; o[i][7] += sv*v1.w;
      }
    }
    #pragma unroll
    for (int i = 0; i < 4; ++i) {
      int r = r0 + i;
      if (r >= 49) continue;
      ushort4 w0, w1;
      w0.x = f2bf(o[i][0]); w0.y = f2bf(o[i][1]); w0.z = f2bf(o[i][2]); w0.w = f2bf(o[i][3]);
      w1.x = f2bf(o[i][4]); w1.y = f2bf(o[i][5]); w1.z = f2bf(o[i][6]); w1.w = f2bf(o[i][7]);
      size_t ob = ((size_t)bw*49 + r)*C2c + h*96 + d0;
      *(ushort4*)&out[ob]     = w0;
      *(ushort4*)&out[ob + 4] = w1;
    }
  }
}

// ---------------- host launcher ----------------
extern "C" void kernel_launch(void* const* d_in, const int* in_sizes, int n_in,
                              void* d_out, int out_size, void* d_ws, size_t ws_size,
                              hipStream_t stream)
{
  const float* x      = (const float*)d_in[0];
  const float* g      = (const float*)d_in[1];
  const float* norm_w = (const float*)d_in[2];
  const float* norm_b = (const float*)d_in[3];
  const float* n1_w   = (const float*)d_in[4];
  const float* n1_b   = (const float*)d_in[5];
  const float* qkv_w  = (const float*)d_in[6];
  const float* qkv_b  = (const float*)d_in[7];
  const float* proj_w = (const float*)d_in[8];
  const float* proj_b = (const float*)d_in[9];
  const float* rpb    = (const float*)d_in[10];
  const float* n2_w   = (const float*)d_in[11];
  const float* n2_b   = (const float*)d_in[12];
  const float* fc1_w  = (const float*)d_in[13];
  const float* fc1_b  = (const float*)d_in[14];
  const float* fc2_w  = (const float*)d_in[15];
  const float* fc2_b  = (const float*)d_in[16];
  const float* conv_w = (const float*)d_in[17];
  const float* conv_b = (const float*)d_in[18];
  float* outp = (float*)d_out;

  // ---- workspace layout (~105.3 MB; validated ws >= 114 MB) ----
  char* p = (char*)d_ws;
  u16* qkvw = (u16*)p; p += 442368*2;
  u16* pw   = (u16*)p; p += 147456*2;
  u16* f1w  = (u16*)p; p += 589824*2;
  u16* f2w  = (u16*)p; p += 589824*2;
  u16* cvwh = (u16*)p; p += (size_t)CONVN*CONVK*2;
  u16* cvwl = (u16*)p; p += (size_t)CONVN*CONVK*2;
  float* musig = (float*)p; p += (size_t)TOKP*2*4;
  u16* zpad = (u16*)p; p += 256;
  u16* wbuf = (u16*)p; p += (size_t)TOKP*C2c*2;                      // 24.39 MB
  char* qr  = p;       p += (size_t)TOKP*1152*2;                     // 73.16 MB (phase 1: qkv bf16)
  u16*   qkvb = (u16*)qr;
  float* z    = (float*)qr;                                          // 44.24 MB (phase 2, overlays qkvb)
  u16*   hid  = (u16*)(qr + (size_t)TOKC*C2c*4);                     // 22.12 MB chunk hidden (fits in qr)

  // one-shot prep: 4 weight casts + conv transpose/split + zero pad
  prep_kernel<<<9505, 256, 0, stream>>>(qkv_w, proj_w, fc1_w, fc2_w, conv_w,
                                        qkvw, pw, f1w, f2w, cvwh, cvwl, zpad);

  // K1a: LN1 stats + LN(n1)+roll+window -> wbuf
  k1a_kernel<<<TOKP, 384, 0, stream>>>(x, g, norm_w, norm_b, n1_w, n1_b, musig, wbuf);

  // qkv GEMM
  mfma_gemm<0><<<dim3(9, 249), 256, 0, stream>>>(
      wbuf, qkvw, qkv_b, qkvb, nullptr, TOKP, 1152, 384, 384, 1);

  // attention
  attn_kernel<<<BATCH*NWc*HEADS, 256, 0, stream>>>(qkvb, rpb, wbuf);

  // K1b: rebuild fp32 residual z (overlays now-dead qkvb)
  k1b_kernel<<<TOKC, 384, 0, stream>>>(x, g, norm_w, norm_b, musig, z);

  // proj GEMM + window-reverse/unshift scatter-add into z
  mfma_gemm<1><<<dim3(3, 249), 256, 0, stream>>>(
      wbuf, pw, proj_b, nullptr, z, TOKP, 384, 384, 384, 1);

  // LN (n2)
  ln2_kernel<<<TOKC, 384, 0, stream>>>(z, n2_w, n2_b, wbuf);

  // MLP hidden-split in 4 col-chunks; final chunk fuses y-bf16 (EPI4, no z write)
  for (int h0 = 0; h0 < MLPH; h0 += 384) {
    mfma_gemm<2><<<dim3(3, 225), 256, 0, stream>>>(
        wbuf, f1w + (size_t)h0*384, fc1_b + h0, hid, nullptr, TOKC, 384, 384, 384, 1);
    if (h0 < MLPH - 384)
      mfma_gemm<3><<<dim3(3, 225), 256, 0, stream>>>(
          hid, f2w + h0, fc2_b, nullptr, z, TOKC, 384, 384, MLPH, h0 == 0 ? 1 : 0);
    else
      mfma_gemm<4><<<dim3(3, 225), 256, 0, stream>>>(
          hid, f2w + h0, fc2_b, wbuf, z, TOKC, 384, 384, MLPH, 0);
  }

  // conv 3x3 im2col MFMA (BM=64, BN=64, BK=128 half-tiled, all-gload_lds) + conv_b + x residual
  mfma_conv<<<dim3(3, 450), 256, 0, stream>>>(wbuf, cvwh, cvwl, conv_b, x, zpad, outp);
}

// Round 12
// 750.711 us; speedup vs baseline: 1.1570x; 1.1570x over previous
//
#include <hip/hip_runtime.h>
#include <cstddef>
#include <cstdint>

// ---------------- problem constants ----------------
#define HEADS   4
#define C2c     384
#define HPc     63
#define WPc     63
#define NWc     81
#define BATCH   8
#define TOKP    (BATCH*HPc*WPc)   // 31752 windowed rows
#define TOKC    (BATCH*60*60)     // 28800 cropped tokens
#define MLPH    1536
#define TPB     3969              // windowed rows per batch
#define CONVK   3456              // 384*9
#define CONVN   192

typedef __attribute__((ext_vector_type(8))) short short8;
typedef __attribute__((ext_vector_type(4))) float f32x4;
typedef unsigned short u16;

__device__ __forceinline__ u16 f2bf(float f) {
  unsigned u = __float_as_uint(f);
  u += 0x7fff + ((u >> 16) & 1);           // RNE
  return (u16)(u >> 16);
}
__device__ __forceinline__ float bf2f(u16 b) { return __uint_as_float((unsigned)b << 16); }

// global -> LDS async 16B: dest = wave-uniform base + lane*16; src per-lane
#define GLOAD16(gp, lp) __builtin_amdgcn_global_load_lds( \
    (const __attribute__((address_space(1))) unsigned*)(gp), \
    (__attribute__((address_space(3))) unsigned*)(lp), 16, 0, 0)

// bijective XCD swizzle (m204)
__device__ __forceinline__ int xcd_swizzle(int orig, int nwg) {
  int q = nwg >> 3, r = nwg & 7;
  int xcd = orig & 7, off = orig >> 3;
  return (xcd < r ? xcd*(q+1) : r*(q+1) + (xcd - r)*q) + off;
}

// ---------------- block reduce (384 threads, 6 waves) ----------------
__device__ __forceinline__ float2 block_reduce_384(float v, float* red) {
  __syncthreads();
  float s = v, q = v * v;
  #pragma unroll
  for (int o = 32; o > 0; o >>= 1) {
    s += __shfl_down(s, o);
    q += __shfl_down(q, o);
  }
  int w = threadIdx.x >> 6;
  if ((threadIdx.x & 63) == 0) { red[2*w] = s; red[2*w+1] = q; }
  __syncthreads();
  float ts = red[0]+red[2]+red[4]+red[6]+red[8]+red[10];
  float tq = red[1]+red[3]+red[5]+red[7]+red[9]+red[11];
  return make_float2(ts, tq);
}

// ---------------- K1a ----------------
__global__ __launch_bounds__(384)
void k1a_kernel(const float* __restrict__ x, const float* __restrict__ g,
                const float* __restrict__ nw, const float* __restrict__ nb,
                const float* __restrict__ n1w, const float* __restrict__ n1b,
                float* __restrict__ musig, u16* __restrict__ wbuf)
{
  __shared__ float red[12];
  int t = blockIdx.x;
  int b = t / (HPc*WPc);
  int rem = t - b*(HPc*WPc);
  int i = rem / WPc, j = rem - (rem / WPc)*WPc;
  int c = threadIdx.x;

  float v = 0.f;
  if (i < 60 && j < 60) {
    if (c < 192) v = x[(((size_t)b*192 + c)*60 + i)*60 + j];
    else         v = g[(((size_t)b*192 + (c-192))*60 + i)*60 + j];
  }
  float2 ss = block_reduce_384(v, red);
  float mu  = ss.x * (1.f/384.f);
  float var = ss.y * (1.f/384.f) - mu*mu;
  float rs  = rsqrtf(var + 1e-5f);
  if (c == 0) { musig[2*t] = mu; musig[2*t+1] = rs; }
  float zi  = (v - mu) * rs * nw[c] + nb[c];
  float2 s2 = block_reduce_384(zi, red);
  float mu2  = s2.x * (1.f/384.f);
  float var2 = s2.y * (1.f/384.f) - mu2*mu2;
  float zn = (zi - mu2) * rsqrtf(var2 + 1e-5f) * n1w[c] + n1b[c];
  int ai = i - 3; if (ai < 0) ai += HPc;
  int aj = j - 3; if (aj < 0) aj += WPc;
  int win = (ai/7)*9 + (aj/7);
  int tok = (ai%7)*7 + (aj%7);
  wbuf[(((size_t)b*NWc + win)*49 + tok)*C2c + c] = f2bf(zn);
}

// ---------------- K1b ----------------
__global__ __launch_bounds__(384)
void k1b_kernel(const float* __restrict__ x, const float* __restrict__ g,
                const float* __restrict__ nw, const float* __restrict__ nb,
                const float* __restrict__ musig, float* __restrict__ z)
{
  int tc = blockIdx.x;
  int b = tc / 3600;
  int rem = tc - b*3600;
  int i = rem / 60, j = rem - (rem/60)*60;
  int t = b*(HPc*WPc) + i*WPc + j;
  int c = threadIdx.x;
  float v;
  if (c < 192) v = x[(((size_t)b*192 + c)*60 + i)*60 + j];
  else         v = g[(((size_t)b*192 + (c-192))*60 + i)*60 + j];
  float mu = musig[2*t], rs = musig[2*t+1];
  z[(size_t)tc*C2c + c] = (v - mu) * rs * nw[c] + nb[c];
}

// ---------------- LN (n2) ----------------
__global__ __launch_bounds__(384)
void ln2_kernel(const float* __restrict__ z, const float* __restrict__ nw,
                const float* __restrict__ nb, u16* __restrict__ out)
{
  __shared__ float red[12];
  int tc = blockIdx.x;
  int c = threadIdx.x;
  float v = z[(size_t)tc*C2c + c];
  float2 ss = block_reduce_384(v, red);
  float mu  = ss.x * (1.f/384.f);
  float var = ss.y * (1.f/384.f) - mu*mu;
  out[(size_t)tc*C2c + c] = f2bf((v - mu) * rsqrtf(var + 1e-5f) * nw[c] + nb[c]);
}

// ---------------- fp32 -> bf16 bulk convert (weight casts) ----------------
__global__ __launch_bounds__(256)
void f2bf_kernel(const float* __restrict__ in, u16* __restrict__ out, int n4)
{
  int t = blockIdx.x*256 + threadIdx.x;
  if (t >= n4) return;
  float4 v = ((const float4*)in)[t];
  ushort4 o;
  o.x = f2bf(v.x); o.y = f2bf(v.y); o.z = f2bf(v.z); o.w = f2bf(v.w);
  ((ushort4*)out)[t] = o;
}

__global__ void zero_kernel(uint4* p) { p[threadIdx.x] = make_uint4(0,0,0,0); }

// conv weight: transpose OIHW -> [oc][p*384+c], split hi/lo
__global__ void split_convw(const float* __restrict__ cw, u16* __restrict__ hi, u16* __restrict__ lo)
{
  int t = blockIdx.x*blockDim.x + threadIdx.x;
  if (t >= CONVN*CONVK) return;
  int oc = t / CONVK, k = t - oc*CONVK;
  int p = k / 384, c = k - p*384;
  float v = cw[((size_t)oc*384 + c)*9 + p];
  u16 h = f2bf(v);
  hi[t] = h;
  lo[t] = f2bf(v - bf2f(h));
}

// ---------------- MFMA GEMM (128x128, BK=64, single bf16 weight, XCD swizzle) ----------------
// EPI 0: bf16 store  EPI 1: z scatter-add (proj)  EPI 2: GELU bf16 (fc1)
// EPI 3: z += val(+bias)  EPI 4: vv = val(+bias)+z; z=vv; Cb=bf16(vv)
template<int EPI>
__global__ __launch_bounds__(256)
void mfma_gemm(const u16* __restrict__ A, const u16* __restrict__ B,
               const float* __restrict__ bias, u16* __restrict__ Cb, float* __restrict__ zbuf,
               int M, int N, int K, int ldb, int addbias)
{
  __shared__ u16 As [128*64];
  __shared__ u16 Bs [128*64];
  int tid = threadIdx.x;
  int lane = tid & 63, w = tid >> 6;
  int wr = w >> 1, wc = w & 1;
  int nwg = gridDim.x * gridDim.y;
  int swz = xcd_swizzle(blockIdx.y*gridDim.x + blockIdx.x, nwg);
  int bx = swz % gridDim.x, by = swz / gridDim.x;
  int m0 = by * 128, n0 = bx * 128;
  int srow = lane >> 3, sslot = (lane & 7) ^ srow;

  f32x4 acc[4][4];
  #pragma unroll
  for (int i = 0; i < 4; ++i)
    #pragma unroll
    for (int j = 0; j < 4; ++j) acc[i][j] = (f32x4){0.f,0.f,0.f,0.f};

  char* AsB = (char*)As; char* BsB = (char*)Bs;
  int r15 = lane & 15, kq = lane >> 4;

  for (int k0 = 0; k0 < K; k0 += 64) {
    #pragma unroll
    for (int i = 0; i < 4; ++i) {
      int rblk = w*4 + i;
      int ar = m0 + rblk*8 + srow; if (ar >= M) ar = M - 1;
      int br = n0 + rblk*8 + srow;
      GLOAD16(A + (size_t)ar*K   + k0 + sslot*8, AsB + rblk*1024);
      GLOAD16(B + (size_t)br*ldb + k0 + sslot*8, BsB + rblk*1024);
    }
    __syncthreads();
    #pragma unroll
    for (int ks = 0; ks < 2; ++ks) {
      int slog = ks*4 + kq;
      short8 af[4], bf[4];
      #pragma unroll
      for (int mi = 0; mi < 4; ++mi) {
        int row = wr*64 + mi*16 + r15;
        af[mi] = *(const short8*)(AsB + row*128 + ((slog ^ (row&7))<<4));
      }
      #pragma unroll
      for (int ni = 0; ni < 4; ++ni) {
        int row = wc*64 + ni*16 + r15;
        bf[ni] = *(const short8*)(BsB + row*128 + ((slog ^ (row&7))<<4));
      }
      #pragma unroll
      for (int mi = 0; mi < 4; ++mi)
        #pragma unroll
        for (int ni = 0; ni < 4; ++ni)
          acc[mi][ni] = __builtin_amdgcn_mfma_f32_16x16x32_bf16(af[mi], bf[ni], acc[mi][ni], 0, 0, 0);
    }
    __syncthreads();
  }

  int fq = lane >> 4, fr = lane & 15;
  #pragma unroll
  for (int mi = 0; mi < 4; ++mi) {
    #pragma unroll
    for (int j = 0; j < 4; ++j) {
      int m = m0 + wr*64 + mi*16 + fq*4 + j;
      if (m >= M) continue;
      int zrow = 0; bool zok = true;
      if (EPI == 1) {
        int b = m / TPB;
        int rem = m - b*TPB;
        int win = rem / 49, tok = rem - (rem/49)*49;
        int wh = win/9, ww = win - (win/9)*9;
        int th = tok/7, tw = tok - (tok/7)*7;
        int oi = wh*7 + th + 3; if (oi >= HPc) oi -= HPc;
        int oj = ww*7 + tw + 3; if (oj >= WPc) oj -= WPc;
        zok = (oi < 60 && oj < 60);
        zrow = (b*60 + oi)*60 + oj;
      }
      #pragma unroll
      for (int ni = 0; ni < 4; ++ni) {
        int n = n0 + wc*64 + ni*16 + fr;
        float val = acc[mi][ni][j];
        if (EPI == 0) {
          Cb[(size_t)m*N + n] = f2bf(val + bias[n]);
        } else if (EPI == 1) {
          if (zok) zbuf[(size_t)zrow*C2c + n] += val + bias[n];
        } else if (EPI == 2) {
          float vv = val + bias[n];
          float ge = 0.5f*vv*(1.f + erff(vv*0.70710678118654752f));
          Cb[(size_t)m*N + n] = f2bf(ge);
        } else if (EPI == 3) {
          float vv = val + (addbias ? bias[n] : 0.f);
          zbuf[(size_t)m*C2c + n] += vv;
        } else { // EPI == 4
          float vv = val + (addbias ? bias[n] : 0.f) + zbuf[(size_t)m*C2c + n];
          zbuf[(size_t)m*C2c + n] = vv;
          Cb[(size_t)m*C2c + n] = f2bf(vv);
        }
      }
    }
  }
}

// ---------------- conv im2col MFMA: BM=64, BN=64, BK=128 as 2x64-col half-tiles ----------------
// Half-tiles keep the 128B LDS row stride (8 slots x 16B = all 32 banks once) -> conflict-free,
// while BK=128 halves the barrier count vs BK=64 (27 K-steps, 32 MFMA/wave/step).
__global__ __launch_bounds__(256)
void mfma_conv(const u16* __restrict__ Y, const u16* __restrict__ Bh, const u16* __restrict__ Bl,
               const float* __restrict__ cb, const float* __restrict__ xres,
               const u16* __restrict__ zpad, float* __restrict__ outp)
{
  __shared__ u16 As [2*64*64];   // 16 KB: [half][64 rows][8 slots x 16B]
  __shared__ u16 Bsh[2*64*64];   // 16 KB
  __shared__ u16 Bsl[2*64*64];   // 16 KB -> 48 KB total
  int tid = threadIdx.x;
  int lane = tid & 63, w = tid >> 6;
  int wr = w >> 1, wc = w & 1;
  int nwg = gridDim.x * gridDim.y;   // 3*450 = 1350
  int swz = xcd_swizzle(blockIdx.y*gridDim.x + blockIdx.x, nwg);
  int bx = swz % 3, by = swz / 3;
  int m0 = by * 64, n0 = bx * 64;
  int srow = lane >> 3, sslot = (lane & 7) ^ srow;   // row-in-chunk, pre-swizzled slot

  f32x4 acc[2][2];
  #pragma unroll
  for (int i = 0; i < 2; ++i)
    #pragma unroll
    for (int j = 0; j < 2; ++j) acc[i][j] = (f32x4){0.f,0.f,0.f,0.f};

  // chunk c (0..15): half = c>>3, rows (c&7)*8 + srow; wave w stages chunks {w, w+4, w+8, w+12}
  int pbA[4], ohA[4], owA[4], colA[4], cA[4];
  #pragma unroll
  for (int i = 0; i < 4; ++i) {
    cA[i] = w + i*4;
    int row = (cA[i] & 7)*8 + srow;
    int pix = m0 + row;
    int pb = pix / 3600;
    int prem = pix - pb*3600;
    pbA[i] = pb; ohA[i] = prem / 60; owA[i] = prem - (prem/60)*60;
    colA[i] = (cA[i] >> 3)*64 + sslot*8;            // half offset + pre-swizzled col
  }
  int brB[4], colB[4], cB[4];
  #pragma unroll
  for (int j = 0; j < 4; ++j) {
    cB[j] = w + j*4;
    brB[j] = n0 + (cB[j] & 7)*8 + srow;             // always < 192
    colB[j] = (cB[j] >> 3)*64 + sslot*8;
  }

  char* AsB = (char*)As; char* BhB = (char*)Bsh; char* BlB = (char*)Bsl;
  int r15 = lane & 15, kq = lane >> 4;

  for (int k0 = 0; k0 < CONVK; k0 += 128) {
    int p  = k0 / 384;                 // tap constant within BK=128 (384 % 128 == 0)
    int c0 = k0 - p*384;
    int dh = p/3 - 1, dw = (p - (p/3)*3) - 1;
    #pragma unroll
    for (int j = 0; j < 4; ++j) {
      GLOAD16(Bh + (size_t)brB[j]*CONVK + k0 + colB[j], BhB + cB[j]*1024);
      GLOAD16(Bl + (size_t)brB[j]*CONVK + k0 + colB[j], BlB + cB[j]*1024);
    }
    #pragma unroll
    for (int i = 0; i < 4; ++i) {
      int ih = ohA[i] + dh, iw = owA[i] + dw;
      const u16* src = ((unsigned)ih < 60u && (unsigned)iw < 60u)
        ? Y + ((size_t)pbA[i]*3600 + ih*60 + iw)*C2c + c0 + colA[i]
        : zpad;
      GLOAD16(src, AsB + cA[i]*1024);
    }
    __syncthreads();
    #pragma unroll
    for (int h = 0; h < 2; ++h) {
      #pragma unroll
      for (int ks = 0; ks < 2; ++ks) {
        int slog = ks*4 + kq;
        short8 af[2], bh2[2], bl2[2];
        #pragma unroll
        for (int mi = 0; mi < 2; ++mi) {
          int row = wr*32 + mi*16 + r15;
          af[mi] = *(const short8*)(AsB + h*8192 + row*128 + ((slog ^ (row&7))<<4));
        }
        #pragma unroll
        for (int ni = 0; ni < 2; ++ni) {
          int row = wc*32 + ni*16 + r15;
          int off = h*8192 + row*128 + ((slog ^ (row&7))<<4);
          bh2[ni] = *(const short8*)(BhB + off);
          bl2[ni] = *(const short8*)(BlB + off);
        }
        #pragma unroll
        for (int mi = 0; mi < 2; ++mi)
          #pragma unroll
          for (int ni = 0; ni < 2; ++ni) {
            acc[mi][ni] = __builtin_amdgcn_mfma_f32_16x16x32_bf16(af[mi], bh2[ni], acc[mi][ni], 0, 0, 0);
            acc[mi][ni] = __builtin_amdgcn_mfma_f32_16x16x32_bf16(af[mi], bl2[ni], acc[mi][ni], 0, 0, 0);
          }
      }
    }
    __syncthreads();
  }

  int fq = lane >> 4, fr = lane & 15;
  #pragma unroll
  for (int mi = 0; mi < 2; ++mi) {
    #pragma unroll
    for (int j = 0; j < 4; ++j) {
      int m = m0 + wr*32 + mi*16 + fq*4 + j;          // pixel id < 28800
      int pb = m / 3600;
      int rem = m - pb*3600;
      int oh = rem / 60, ow = rem - (rem/60)*60;
      #pragma unroll
      for (int ni = 0; ni < 2; ++ni) {
        int oc = n0 + wc*32 + ni*16 + fr;             // < 192
        size_t oi = ((size_t)pb*192 + oc)*3600 + oh*60 + ow;
        outp[oi] = acc[mi][ni][j] + cb[oc] + xres[oi];
      }
    }
  }
}

// ---------------- windowed attention (register-tiled) ----------------
#define QS_STRIDE 100
#define VS_STRIDE 104
#define SS_STRIDE 53

__global__ __launch_bounds__(256)
void attn_kernel(const u16* __restrict__ qkv, const float* __restrict__ rpb,
                 u16* __restrict__ out)
{
  __shared__ float qs[52*QS_STRIDE];
  __shared__ float ks[52*QS_STRIDE];
  __shared__ float S[52*SS_STRIDE];
  int blk = blockIdx.x;
  int h   = blk & 3;
  int bw  = blk >> 2;
  int win = bw % NWc;
  const u16* base = qkv + (size_t)bw*49*1152;
  int tid = threadIdx.x;

  for (int t2 = tid; t2 < 588; t2 += 256) {
    int r = t2 / 12, dq = t2 - (t2/12)*12;
    short8 qv = *(const short8*)(base + r*1152 +       h*96 + dq*8);
    short8 kv = *(const short8*)(base + r*1152 + 384 + h*96 + dq*8);
    #pragma unroll
    for (int e = 0; e < 8; ++e) {
      qs[r*QS_STRIDE + dq*8 + e] = bf2f((u16)qv[e]);
      ks[r*QS_STRIDE + dq*8 + e] = bf2f((u16)kv[e]);
    }
  }
  __syncthreads();

  const float scale = 0.1020620726159657f;
  int wh = win / 9, ww = win - (win/9)*9;

  if (tid < 169) {
    int tr = tid / 13, tc = tid - (tid/13)*13;
    int r0 = tr*4, c0 = tc*4;
    float a[4][4] = {};
    for (int k0 = 0; k0 < 96; k0 += 4) {
      float4 qv[4], kv4[4];
      #pragma unroll
      for (int i = 0; i < 4; ++i) qv[i]  = *(const float4*)&qs[(r0+i)*QS_STRIDE + k0];
      #pragma unroll
      for (int j = 0; j < 4; ++j) kv4[j] = *(const float4*)&ks[(c0+j)*QS_STRIDE + k0];
      #pragma unroll
      for (int i = 0; i < 4; ++i)
        #pragma unroll
        for (int j = 0; j < 4; ++j)
          a[i][j] += qv[i].x*kv4[j].x + qv[i].y*kv4[j].y + qv[i].z*kv4[j].z + qv[i].w*kv4[j].w;
    }
    #pragma unroll
    for (int i = 0; i < 4; ++i) {
      int r = r0 + i;
      if (r < 49) {
        int r1 = r/7, c1 = r - (r/7)*7;
        int hp1 = wh*7 + r1, wp1 = ww*7 + c1;
        int g1 = (hp1 < 56 ? 0 : (hp1 < 60 ? 1 : 2))*3 + (wp1 < 56 ? 0 : (wp1 < 60 ? 1 : 2));
        #pragma unroll
        for (int j = 0; j < 4; ++j) {
          int c = c0 + j;
          if (c < 49) {
            int r2 = c/7, c2 = c - (c/7)*7;
            float s = a[i][j]*scale + rpb[((r1 - r2 + 6)*13 + (c1 - c2 + 6))*HEADS + h];
            int hp2 = wh*7 + r2, wp2 = ww*7 + c2;
            int g2 = (hp2 < 56 ? 0 : (hp2 < 60 ? 1 : 2))*3 + (wp2 < 56 ? 0 : (wp2 < 60 ? 1 : 2));
            if (g1 != g2) s -= 100.f;
            S[r*SS_STRIDE + c] = s;
          }
        }
      }
    }
  }
  __syncthreads();

  for (int t2 = tid; t2 < 588; t2 += 256) {
    int r = t2 / 12, dq = t2 - (t2/12)*12;
    short8 vv = *(const short8*)(base + r*1152 + 768 + h*96 + dq*8);
    #pragma unroll
    for (int e = 0; e < 8; ++e) ks[r*VS_STRIDE + dq*8 + e] = bf2f((u16)vv[e]);
  }
  if (tid < 49) {
    float mx = -1e30f;
    for (int c = 0; c < 49; ++c) mx = fmaxf(mx, S[tid*SS_STRIDE + c]);
    float sum = 0.f;
    for (int c = 0; c < 49; ++c) { float e = expf(S[tid*SS_STRIDE + c] - mx); S[tid*SS_STRIDE + c] = e; sum += e; }
    float inv = 1.f / sum;
    for (int c = 0; c < 49; ++c) S[tid*SS_STRIDE + c] *= inv;
  }
  __syncthreads();

  if (tid < 156) {
    int tr2 = tid / 12, tc2 = tid - (tid/12)*12;
    int r0 = tr2*4, d0 = tc2*8;
    float o[4][8] = {};
    for (int c = 0; c < 49; ++c) {
      float4 v0 = *(const float4*)&ks[c*VS_STRIDE + d0];
      float4 v1 = *(const float4*)&ks[c*VS_STRIDE + d0 + 4];
      #pragma unroll
      for (int i = 0; i < 4; ++i) {
        float sv = S[(r0+i)*SS_STRIDE + c];
        o[i][0] += sv*v0.x; o[i][1] += sv*v0.y; o[i][2] += sv*v0.z; o[i][3] += sv*v0.w;
        o[i][4] += sv*v1.x; o[i][5] += sv*v1.y; o[i][6] += sv*v1.z; o[i][7] += sv*v1.w;
      }
    }
    #pragma unroll
    for (int i = 0; i < 4; ++i) {
      int r = r0 + i;
      if (r >= 49) continue;
      ushort4 w0, w1;
      w0.x = f2bf(o[i][0]); w0.y = f2bf(o[i][1]); w0.z = f2bf(o[i][2]); w0.w = f2bf(o[i][3]);
      w1.x = f2bf(o[i][4]); w1.y = f2bf(o[i][5]); w1.z = f2bf(o[i][6]); w1.w = f2bf(o[i][7]);
      size_t ob = ((size_t)bw*49 + r)*C2c + h*96 + d0;
      *(ushort4*)&out[ob]     = w0;
      *(ushort4*)&out[ob + 4] = w1;
    }
  }
}

// ---------------- host launcher ----------------
extern "C" void kernel_launch(void* const* d_in, const int* in_sizes, int n_in,
                              void* d_out, int out_size, void* d_ws, size_t ws_size,
                              hipStream_t stream)
{
  const float* x      = (const float*)d_in[0];
  const float* g      = (const float*)d_in[1];
  const float* norm_w = (const float*)d_in[2];
  const float* norm_b = (const float*)d_in[3];
  const float* n1_w   = (const float*)d_in[4];
  const float* n1_b   = (const float*)d_in[5];
  const float* qkv_w  = (const float*)d_in[6];
  const float* qkv_b  = (const float*)d_in[7];
  const float* proj_w = (const float*)d_in[8];
  const float* proj_b = (const float*)d_in[9];
  const float* rpb    = (const float*)d_in[10];
  const float* n2_w   = (const float*)d_in[11];
  const float* n2_b   = (const float*)d_in[12];
  const float* fc1_w  = (const float*)d_in[13];
  const float* fc1_b  = (const float*)d_in[14];
  const float* fc2_w  = (const float*)d_in[15];
  const float* fc2_b  = (const float*)d_in[16];
  const float* conv_w = (const float*)d_in[17];
  const float* conv_b = (const float*)d_in[18];
  float* outp = (float*)d_out;

  // ---- workspace layout (wbuf-first; identical to the 745-us baseline) ----
  char* p = (char*)d_ws;
  u16* wbuf = (u16*)p;              p += (size_t)TOKP*C2c*2;        // 24.39 MB
  char* qr  = p;                    p += (size_t)TOKP*1152*2;       // 73.16 MB qkv bf16 (phase 1)
  u16*   qkvb = (u16*)qr;
  float* z    = (float*)qr;                                          // 44.24 MB fp32 residual (phase 2)
  u16*   hid_c = (u16*)(qr + (size_t)TOKC*C2c*4);                    // 29.49 MB chunk hidden (overruns into qkvw)
  u16* qkvw = (u16*)p; p += 442368*2;                                // dead after qkv GEMM
  u16* pw   = (u16*)p; p += 147456*2;
  u16* f1w  = (u16*)p; p += 589824*2;
  u16* f2w  = (u16*)p; p += 589824*2;
  u16* cvwh = (u16*)p; p += (size_t)CONVN*CONVK*2;
  u16* cvwl = (u16*)p; p += (size_t)CONVN*CONVK*2;
  float* musig = (float*)p; p += (size_t)TOKP*2*4;
  u16* zpad = (u16*)p; p += 256;                                     // zero pad for conv OOB taps
  u16* hid_f = (u16*)p;                                              // full hidden (88.5 MB) if ws allows
  size_t need_full = (size_t)(p - (char*)d_ws) + (size_t)TOKC*MLPH*2;
  bool full_mlp = ws_size >= need_full;

  // weight casts + conv split + zero pad
  f2bf_kernel<<<(442368/4 + 255)/256, 256, 0, stream>>>(qkv_w, qkvw, 442368/4);
  f2bf_kernel<<<(147456/4 + 255)/256, 256, 0, stream>>>(proj_w, pw, 147456/4);
  f2bf_kernel<<<(589824/4 + 255)/256, 256, 0, stream>>>(fc1_w, f1w, 589824/4);
  f2bf_kernel<<<(589824/4 + 255)/256, 256, 0, stream>>>(fc2_w, f2w, 589824/4);
  split_convw<<<(CONVN*CONVK + 255)/256, 256, 0, stream>>>(conv_w, cvwh, cvwl);
  zero_kernel<<<1, 16, 0, stream>>>((uint4*)zpad);

  // K1a
  k1a_kernel<<<TOKP, 384, 0, stream>>>(x, g, norm_w, norm_b, n1_w, n1_b, musig, wbuf);

  // qkv GEMM
  mfma_gemm<0><<<dim3(9, 249), 256, 0, stream>>>(
      wbuf, qkvw, qkv_b, qkvb, nullptr, TOKP, 1152, 384, 384, 1);

  // attention
  attn_kernel<<<BATCH*NWc*HEADS, 256, 0, stream>>>(qkvb, rpb, wbuf);

  // K1b: rebuild fp32 residual z
  k1b_kernel<<<TOKC, 384, 0, stream>>>(x, g, norm_w, norm_b, musig, z);

  // proj GEMM + scatter-add into z
  mfma_gemm<1><<<dim3(3, 249), 256, 0, stream>>>(
      wbuf, pw, proj_b, nullptr, z, TOKP, 384, 384, 384, 1);

  // LN (n2)
  ln2_kernel<<<TOKC, 384, 0, stream>>>(z, n2_w, n2_b, wbuf);

  if (full_mlp) {
    mfma_gemm<2><<<dim3(12, 225), 256, 0, stream>>>(
        wbuf, f1w, fc1_b, hid_f, nullptr, TOKC, MLPH, 384, 384, 1);
    mfma_gemm<4><<<dim3(3, 225), 256, 0, stream>>>(
        hid_f, f2w, fc2_b, wbuf, z, TOKC, 384, MLPH, MLPH, 1);
  } else {
    // M-chunked MLP: 3 chunks of 9600 tokens, full hidden width, z RMW once
    const int CH = 9600;   // 75 * 128
    for (int off = 0; off < TOKC; off += CH) {
      mfma_gemm<2><<<dim3(12, 75), 256, 0, stream>>>(
          wbuf + (size_t)off*C2c, f1w, fc1_b, hid_c, nullptr, CH, MLPH, 384, 384, 1);
      mfma_gemm<4><<<dim3(3, 75), 256, 0, stream>>>(
          hid_c, f2w, fc2_b, wbuf + (size_t)off*C2c, z + (size_t)off*C2c, CH, 384, MLPH, MLPH, 1);
    }
  }

  // conv 3x3 im2col MFMA (BM=64, BN=64, BK=128 half-tiled, all-gload_lds, conflict-free)
  mfma_conv<<<dim3(3, 450), 256, 0, stream>>>(wbuf, cvwh, cvwl, conv_b, x, zpad, outp);
}